// Round 25
// baseline (84.164 us; speedup 1.0000x reference)
//
#include <hip/hip_runtime.h>
#include <hip/hip_bf16.h>

// MultiHeadLinearAttention2D on MI355X (gfx950), bf16-MFMA implementation.
// B=16, C_in=C_out=256, H=W=64 (M=4096), heads=8, dh=32, scale=1/sqrt(32).
//
// Round-25: xkv at 1024 threads = 16 waves/block -> 32 waves/CU (the HW
// max; every variant since R7 ran 16 waves/CU). Wave w = (head w>>1,
// m-half w&1): each wave does one 32-m group per subtile. KV partials go
// per-(chunk,half) -> kvp [b][64][8][1024]; k_red loops 64 (R19's code).
// Staging re-indexed for 1024 threads (16 floats/thread, 2 dump frags).
// wconv / k_q / ximg layout unchanged from R22/R24 (70.8us baseline).

typedef __attribute__((ext_vector_type(8))) short bf16x8;
typedef __attribute__((ext_vector_type(4))) float f32x4;
typedef __attribute__((ext_vector_type(4))) unsigned int u32x4;
typedef __attribute__((ext_vector_type(4))) float float4v;

#define DEVI static __device__ __forceinline__

DEVI unsigned short f2bf(float f){
  __hip_bfloat16 h = __float2bfloat16(f);          // RNE, compiler-lowered
  return __builtin_bit_cast(unsigned short, h);
}
DEVI unsigned int pk2(float a, float b){           // lo=bf16(a), hi=bf16(b)
  return (unsigned int)f2bf(a) | ((unsigned int)f2bf(b) << 16);
}
DEVI float feat(float p){   // (elu(p)+1) * 1/sqrt(32)
  return (p > 0.f ? p + 1.f : __expf(p)) * 0.17677669529663687f;
}

DEVI f32x4 mfma16(u32x4 a, u32x4 b, f32x4 c){
  return __builtin_amdgcn_mfma_f32_16x16x32_bf16(
      __builtin_bit_cast(bf16x8, a), __builtin_bit_cast(bf16x8, b), c, 0, 0, 0);
}

// byte-XOR swizzle (G4) for 512B rows of the LDS x^T image
DEVI int swz8(int m){ return ((m ^ (m >> 3)) & 7) << 4; }

// async global->LDS, 16B per lane; LDS base must be wave-uniform
typedef __attribute__((address_space(3))) unsigned int as3_u32;
typedef __attribute__((address_space(1))) const unsigned int as1_u32;
DEVI void gload16(const void* g, void* l){
  __builtin_amdgcn_global_load_lds((as1_u32*)g, (as3_u32*)l, 16, 0, 0);
}
// stage one 32KB linear image (global -> LDS), async, 8 waves cooperative
DEVI void stage_tile(const char* src, void* buf, int w, int lane){
  #pragma unroll
  for (int i = 0; i < 4; ++i){
    int ub = w * 1024 + i * 8192;               // wave-uniform LDS base
    gload16(src + ub + lane * 16, (char*)buf + ub);
  }
}

// --- 1024-thread staging: fp32 x-tile [256c][64m] -> swizzled bf16 LDS ------
DEVI void stage_load1k(const float* __restrict__ xb, int m0, int tid, float4v* r){
  int cq = tid >> 4;                  // 0..63 -> c0 = 4*cq
  int mq = tid & 15;                  // 0..15 -> ml0 = 4*mq
  const float* p = xb + (size_t)(cq * 4) * 4096 + m0 + mq * 4;
  r[0] = *(const float4v*)(p);
  r[1] = *(const float4v*)(p + 4096);
  r[2] = *(const float4v*)(p + 8192);
  r[3] = *(const float4v*)(p + 12288);
}
DEVI void stage_write1k(unsigned short* xT, int tid, const float4v* r){
  int cq = tid >> 4;
  int mq = tid & 15;
  int c0 = cq * 4, ml0 = mq * 4;
  #pragma unroll
  for (int j = 0; j < 4; ++j){
    int m = ml0 + j;
    unsigned int lo = pk2(r[0][j], r[1][j]);
    unsigned int hi = pk2(r[2][j], r[3][j]);
    int off = m * 512 + ((c0 * 2) ^ swz8(m));
    unsigned long long v = (unsigned long long)lo | ((unsigned long long)hi << 32);
    *(unsigned long long*)((char*)xT + off) = v;
  }
}
// de-swizzle dump (1024 threads): LDS x^T tile -> global frag-order image
DEVI void dump_tile_1k(const unsigned short* xT, unsigned short* dst, int tid){
  #pragma unroll
  for (int i = 0; i < 2; ++i){
    int f = i * 1024 + tid;            // frag index 0..2047
    int lane = f & 63, nt = (f >> 6) & 3, kk = f >> 8;
    int m = nt * 16 + (lane & 15);
    int col = (kk * 64 + (lane >> 4) * 16) ^ swz8(m);
    u32x4 v = *(const u32x4*)((const char*)xT + m * 512 + col);
    *(u32x4*)((char*)dst + (size_t)f * 16) = v;
  }
}

// ---------------- kernel 0: weights -> bf16 fragment-order pack -------------
// wkvf: [h][ot 0..3][kk 0..7][lane 0..63] x 16B ; ot 0,1 = Wk rows, 2,3 = Wv.
// wqf : [h][ot 0..1][kk 0..7][lane 0..63] x 16B.
__global__ void wconv(const float* __restrict__ wq, const float* __restrict__ wk,
                      const float* __restrict__ wv,
                      unsigned short* __restrict__ wkvf, unsigned short* __restrict__ wqf){
  int t = blockIdx.x * 256 + threadIdx.x;   // 24576 threads
  if (t < 16384){                           // wkvf frag slots
    int lane = t & 63, kk = (t >> 6) & 7, ot = (t >> 9) & 3, h = t >> 11;
    int l15 = lane & 15, hi = lane >> 4;
    const float* src = (ot < 2) ? (wk + (size_t)(h * 32 + ot * 16 + l15) * 256)
                                : (wv + (size_t)(h * 32 + (ot - 2) * 16 + l15) * 256);
    src += kk * 32 + hi * 8;
    unsigned short* dst = wkvf + (size_t)t * 8;
    #pragma unroll
    for (int j = 0; j < 8; ++j) dst[j] = f2bf(src[j]);
  } else if (t < 24576){                    // wqf frag slots
    int u = t - 16384;
    int lane = u & 63, kk = (u >> 6) & 7, ot = (u >> 9) & 1, h = u >> 10;
    int l15 = lane & 15, hi = lane >> 4;
    const float* src = wq + (size_t)(h * 32 + ot * 16 + l15) * 256 + kk * 32 + hi * 8;
    unsigned short* dst = wqf + (size_t)u * 8;
    #pragma unroll
    for (int j = 0; j < 8; ++j) dst[j] = f2bf(src[j]);
  }
}

// --- one 32-m group from the SWIZZLED LDS tile: K/V projection + fold -------
// Wave computes head h, m-group g (g = its m-half). One fold per call.
DEVI void compute_half_sw(const unsigned short* __restrict__ xT,
                          const unsigned short* __restrict__ wkvf,
                          int h, int g, int l15, int hi, int lane,
                          f32x4 (&kvacc)[2][2], f32x4 (&ksacc)[2], u32x4 ones){
  f32x4 acc[2][4];                        // [n2][ot: 0,1=K, 2,3=V]
  #pragma unroll
  for (int a1 = 0; a1 < 2; ++a1)
    #pragma unroll
    for (int a2 = 0; a2 < 4; ++a2) acc[a1][a2] = f32x4{0.f,0.f,0.f,0.f};

  #pragma unroll
  for (int kk = 0; kk < 8; ++kk){
    u32x4 xf[2];
    #pragma unroll
    for (int n2 = 0; n2 < 2; ++n2){
      int m = (g * 2 + n2) * 16 + l15;
      xf[n2] = *(const u32x4*)((const char*)xT + m * 512 + ((kk * 64 + hi * 16) ^ swz8(m)));
    }
    #pragma unroll
    for (int ot = 0; ot < 4; ++ot){
      u32x4 wf = *(const u32x4*)(wkvf + ((((size_t)h * 4 + ot) * 8 + kk) * 64 + lane) * 8);
      #pragma unroll
      for (int n2 = 0; n2 < 2; ++n2) acc[n2][ot] = mfma16(xf[n2], wf, acc[n2][ot]);
    }
  }
  // pack bf16 frags in-register; fold into KV / ksum accumulators
  u32x4 kf[2], vf[2];
  #pragma unroll
  for (int t2 = 0; t2 < 2; ++t2){
    kf[t2][0] = pk2(feat(acc[0][t2][0]), feat(acc[0][t2][1]));
    kf[t2][1] = pk2(feat(acc[0][t2][2]), feat(acc[0][t2][3]));
    kf[t2][2] = pk2(feat(acc[1][t2][0]), feat(acc[1][t2][1]));
    kf[t2][3] = pk2(feat(acc[1][t2][2]), feat(acc[1][t2][3]));
    vf[t2][0] = pk2(acc[0][t2+2][0], acc[0][t2+2][1]);
    vf[t2][1] = pk2(acc[0][t2+2][2], acc[0][t2+2][3]);
    vf[t2][2] = pk2(acc[1][t2+2][0], acc[1][t2+2][1]);
    vf[t2][3] = pk2(acc[1][t2+2][2], acc[1][t2+2][3]);
  }
  #pragma unroll
  for (int ct = 0; ct < 2; ++ct){
    #pragma unroll
    for (int dt = 0; dt < 2; ++dt)
      kvacc[ct][dt] = mfma16(kf[ct], vf[dt], kvacc[ct][dt]);
    ksacc[ct] = mfma16(kf[ct], ones, ksacc[ct]);
  }
}

// ---------------- kernel 1: FUSED x-convert + ximg dump + K/V partials ------
// grid (32 chunks, 16 batches), 1024 threads = 16 waves; wave = (head, half).
// 2 blocks/CU x 16 waves = 32 waves/CU (HW max).
__global__ void __launch_bounds__(1024) xkv(const float* __restrict__ x,
        const unsigned short* __restrict__ wkvf,
        unsigned short* __restrict__ ximg,
        float* __restrict__ kvp, float* __restrict__ ksp){
  __shared__ __align__(16) unsigned short xT[2][16384];   // 64KB double-buffer
  const int tid = threadIdx.x, lane = tid & 63, w = tid >> 6;
  const int l15 = lane & 15, hi = lane >> 4;
  const int h = w >> 1, half = w & 1;
  const int ch = blockIdx.x, b = blockIdx.y;
  const float* xb = x + (size_t)b * (256 * 4096);
  unsigned short* img = ximg + ((size_t)b * 64 + ch * 2) * 16384;

  f32x4 kvacc[2][2];
  f32x4 ksacc[2];
  #pragma unroll
  for (int i = 0; i < 2; ++i){
    ksacc[i] = f32x4{0.f,0.f,0.f,0.f};
    #pragma unroll
    for (int j = 0; j < 2; ++j) kvacc[i][j] = f32x4{0.f,0.f,0.f,0.f};
  }
  u32x4 ones = {0u,0u,0u,0u};               // B-frag: column d=0 all-ones -> ksum
  if (l15 == 0){ ones[0] = ones[1] = ones[2] = ones[3] = 0x3f803f80u; }

  float4v rs[4];
  stage_load1k(xb, ch * 128, tid, rs);
  stage_write1k(xT[0], tid, rs);
  __syncthreads();                                    // tile 0 ready
  stage_load1k(xb, ch * 128 + 64, tid, rs);           // issue tile-1 loads early
  compute_half_sw(xT[0], wkvf, h, half, l15, hi, lane, kvacc, ksacc, ones);
  dump_tile_1k(xT[0], img, tid);                      // dump after MFMA issue
  stage_write1k(xT[1], tid, rs);                      // write late (latency hidden)
  __syncthreads();                                    // tile 1 ready
  compute_half_sw(xT[1], wkvf, h, half, l15, hi, lane, kvacc, ksacc, ones);
  dump_tile_1k(xT[1], img + 16384, tid);

  // partial stores: kvp [b][64 slot=ch*2+half][8 h][32 c][32 d]
  size_t base = (((size_t)b * 64 + ch * 2 + half) * 8 + h) * 1024;
  #pragma unroll
  for (int ct = 0; ct < 2; ++ct){
    #pragma unroll
    for (int dt = 0; dt < 2; ++dt){
      #pragma unroll
      for (int r = 0; r < 4; ++r){
        int c = ct * 16 + hi * 4 + r, d = dt * 16 + l15;
        kvp[base + c * 32 + d] = kvacc[ct][dt][r];
      }
    }
  }
  if (l15 == 0){
    size_t kb = (((size_t)b * 64 + ch * 2 + half) * 8 + h) * 32;
    #pragma unroll
    for (int ct = 0; ct < 2; ++ct)
      #pragma unroll
      for (int r = 0; r < 4; ++r) ksp[kb + ct * 16 + hi * 4 + r] = ksacc[ct][r];
  }
}

// ---------------- kernel 2: reduce partials -> KV^T bf16 [b][h][d][pos(c)], ksum bf16
// slot permutation matching q's in-register frag: pos(c) = ((c>>2)&3)*8 + (c>>4)*4 + (c&3)
__global__ void k_red(const float* __restrict__ kvp, const float* __restrict__ ksp,
                      unsigned short* __restrict__ kvt, unsigned short* __restrict__ ksb){
  int t = blockIdx.x * 256 + threadIdx.x;   // 32768 threads: (b,h,c,dq)
  int dq = t & 7;            // d-quad
  int c  = (t >> 3) & 31;
  int h  = (t >> 8) & 7;
  int b  = t >> 11;
  float4v s = {0.f,0.f,0.f,0.f};
  for (int c2 = 0; c2 < 64; ++c2){
    const float* p = kvp + ((((size_t)b * 64 + c2) * 8 + h) * 1024) + c * 32 + dq * 4;
    float4v r = *(const float4v*)p;
    s.x += r.x; s.y += r.y; s.z += r.z; s.w += r.w;
  }
  int pos = ((c >> 2) & 3) * 8 + ((c >> 4) << 2) + (c & 3);
  unsigned short* q = kvt + ((size_t)b * 8 + h) * 1024;
  q[(dq * 4 + 0) * 32 + pos] = f2bf(s.x);
  q[(dq * 4 + 1) * 32 + pos] = f2bf(s.y);
  q[(dq * 4 + 2) * 32 + pos] = f2bf(s.z);
  q[(dq * 4 + 3) * 32 + pos] = f2bf(s.w);
  if (dq == 0){
    float ks = 0.f;
    for (int c2 = 0; c2 < 64; ++c2)
      ks += ksp[(((size_t)b * 64 + c2) * 8 + h) * 32 + c];
    ksb[((size_t)b * 8 + h) * 32 + pos] = f2bf(ks);
  }
}

// --- one 64-m subtile of k_q: Q projection + out = KV^T q / denom -----------
// xT = frag-order tile in LDS (linear); fragment reads are contiguous 1KB
// wave reads -> conflict-free, no swizzle.
DEVI void q_sub(const unsigned short* __restrict__ xT,
                const unsigned short* __restrict__ wqf,
                u32x4 afkv0, u32x4 afkv1, u32x4 afd,
                int w, int l15, int hi, int lane, float* __restrict__ ob){
  f32x4 qa[2][4];                           // [ot = c-tile][nt = m-tile]
  #pragma unroll
  for (int a1 = 0; a1 < 2; ++a1)
    #pragma unroll
    for (int a2 = 0; a2 < 4; ++a2) qa[a1][a2] = f32x4{0.f,0.f,0.f,0.f};

  #pragma unroll
  for (int kk = 0; kk < 8; ++kk){
    u32x4 xf[4];
    #pragma unroll
    for (int nt = 0; nt < 4; ++nt)
      xf[nt] = *(const u32x4*)(xT + (((size_t)kk * 4 + nt) * 64 + lane) * 8);
    #pragma unroll
    for (int ot = 0; ot < 2; ++ot){
      u32x4 wf = *(const u32x4*)(wqf + ((((size_t)w * 2 + ot) * 8 + kk) * 64 + lane) * 8);
      #pragma unroll
      for (int nt = 0; nt < 4; ++nt) qa[ot][nt] = mfma16(wf, xf[nt], qa[ot][nt]);
    }
  }

  #pragma unroll
  for (int nt = 0; nt < 4; ++nt){
    // q B-frag in-register: lane l15 = m, slots = c (ot0 r0..3, ot1 r0..3)
    u32x4 bq;
    bq[0] = pk2(feat(qa[0][nt][0]), feat(qa[0][nt][1]));
    bq[1] = pk2(feat(qa[0][nt][2]), feat(qa[0][nt][3]));
    bq[2] = pk2(feat(qa[1][nt][0]), feat(qa[1][nt][1]));
    bq[3] = pk2(feat(qa[1][nt][2]), feat(qa[1][nt][3]));

    f32x4 o0 = {0.f,0.f,0.f,0.f}, o1 = {0.f,0.f,0.f,0.f}, dn = {0.f,0.f,0.f,0.f};
    o0 = mfma16(afkv0, bq, o0);
    o1 = mfma16(afkv1, bq, o1);
    dn = mfma16(afd, bq, dn);
    float dv = __shfl(dn[0], l15, 64);       // lanes hi==0 hold denom[m] in reg0
    float inv = 1.0f / fmaxf(dv, 1e-6f);
    #pragma unroll
    for (int r = 0; r < 4; ++r){
      ob[(size_t)(hi * 4 + r) * 4096 + nt * 16 + l15]      = o0[r] * inv;
      ob[(size_t)(16 + hi * 4 + r) * 4096 + nt * 16 + l15] = o1[r] * inv;
    }
  }
}

// ---------------- kernel 3: Q projection + apply KV -------------------------
// grid (32 chunks, 16 batches), 512 threads = 8 waves = 8 heads; 2 subtiles.
// gload_lds staged, linear frag-order copy (at BW roofline since R10).
__global__ void __launch_bounds__(512) k_q(const unsigned short* __restrict__ ximg,
        const unsigned short* __restrict__ wqf,
        const unsigned short* __restrict__ kvt,
        const unsigned short* __restrict__ ksb,
        float* __restrict__ out){
  __shared__ __align__(16) unsigned short xT[2][16384];   // 64KB double-buffer
  const int tid = threadIdx.x, lane = tid & 63, w = tid >> 6;
  const int l15 = lane & 15, hi = lane >> 4;
  const int ch = blockIdx.x, b = blockIdx.y;
  const char* src = (const char*)(ximg + ((size_t)b * 64 + ch * 2) * 16384);

  // KV^T / ksum frags (slot-permuted storage from k_red matches q packing)
  size_t kvbase = ((size_t)b * 8 + w) * 1024;
  u32x4 afkv0 = *(const u32x4*)(kvt + kvbase + (size_t)l15 * 32 + hi * 8);        // d = l15
  u32x4 afkv1 = *(const u32x4*)(kvt + kvbase + (size_t)(16 + l15) * 32 + hi * 8); // d = 16+l15
  u32x4 afd = {0u,0u,0u,0u};                 // row0 = ksum -> D[0][m] = denom
  if (l15 == 0) afd = *(const u32x4*)(ksb + ((size_t)b * 8 + w) * 32 + hi * 8);

  stage_tile(src, xT[0], w, lane);
  __syncthreads();                                   // t0 ready
  stage_tile(src + 32768, xT[1], w, lane);           // issue t1 async

  float* ob = out + ((size_t)b * 256 + w * 32) * 4096 + ch * 128;
  q_sub(xT[0], wqf, afkv0, afkv1, afd, w, l15, hi, lane, ob);
  __syncthreads();                                   // t1 drained
  q_sub(xT[1], wqf, afkv0, afkv1, afd, w, l15, hi, lane, ob + 64);
}

extern "C" void kernel_launch(void* const* d_in, const int* in_sizes, int n_in,
                              void* d_out, int out_size, void* d_ws, size_t ws_size,
                              hipStream_t stream) {
  const float* x  = (const float*)d_in[0];
  const float* wq = (const float*)d_in[1];
  const float* wk = (const float*)d_in[2];
  const float* wv = (const float*)d_in[3];
  float* out = (float*)d_out;
  char* ws = (char*)d_ws;

  // ws layout (bytes): total ~69 MB
  unsigned short* wkvf = (unsigned short*)(ws);                  // 262144
  unsigned short* wqf  = (unsigned short*)(ws + 262144);         // 131072
  unsigned short* kvt  = (unsigned short*)(ws + 393216);         // 262144
  unsigned short* ksb  = (unsigned short*)(ws + 655360);         // 8192
  float* kvp = (float*)(ws + 1048576);                           // 16*64*8*1024*4 = 33554432
  float* ksp = (float*)(ws + 1048576 + 33554432);                // 16*64*8*32*4 = 1048576
  unsigned short* ximg = (unsigned short*)(ws + 1048576 + 33554432 + 1048576); // 33554432

  hipLaunchKernelGGL(wconv, dim3(96), dim3(256), 0, stream, wq, wk, wv, wkvf, wqf);
  hipLaunchKernelGGL(xkv,   dim3(32, 16), dim3(1024), 0, stream, x, wkvf, ximg, kvp, ksp);
  hipLaunchKernelGGL(k_red, dim3(128), dim3(256), 0, stream, kvp, ksp, kvt, ksb);
  hipLaunchKernelGGL(k_q,   dim3(32, 16), dim3(512), 0, stream, ximg, wqf, kvt, ksb, out);
}

// Round 26
// 70.429 us; speedup vs baseline: 1.1950x; 1.1950x over previous
//
#include <hip/hip_runtime.h>
#include <hip/hip_bf16.h>

// MultiHeadLinearAttention2D on MI355X (gfx950), bf16-MFMA implementation.
// B=16, C_in=C_out=256, H=W=64 (M=4096), heads=8, dh=32, scale=1/sqrt(32).
//
// FINAL = R22/R24 configuration (measured 70.9 / 70.8 us, absmax 4.9e-4).
// Pipeline: wconv (frag-order bf16 weight pack) -> xkv (fused fp32->bf16
// convert + frag-order ximg dump + K/V projection + KV/ksum partials) ->
// k_red (partial reduce -> KV^T/ksum bf16, slot-permuted) -> k_q
// (gload_lds-staged Q projection + apply + denom divide).
// Session findings baked in: MFMA operand-order chaining (no LDS transpose
// round-trips), fragment-order operand images (coalesced lane*16 loads),
// global_load_lds staging for consumers, never launch_bounds' 2nd arg
// (VGPR clamp -> spill), 8-wave blocks at 2 blocks/CU (16 waves/CU optimum:
// more waves (R25), more blocks (R19), finer blocks (R9/R13) all regress).

typedef __attribute__((ext_vector_type(8))) short bf16x8;
typedef __attribute__((ext_vector_type(4))) float f32x4;
typedef __attribute__((ext_vector_type(4))) unsigned int u32x4;
typedef __attribute__((ext_vector_type(4))) float float4v;

#define DEVI static __device__ __forceinline__

DEVI unsigned short f2bf(float f){
  __hip_bfloat16 h = __float2bfloat16(f);          // RNE, compiler-lowered
  return __builtin_bit_cast(unsigned short, h);
}
DEVI unsigned int pk2(float a, float b){           // lo=bf16(a), hi=bf16(b)
  return (unsigned int)f2bf(a) | ((unsigned int)f2bf(b) << 16);
}
DEVI float feat(float p){   // (elu(p)+1) * 1/sqrt(32)
  return (p > 0.f ? p + 1.f : __expf(p)) * 0.17677669529663687f;
}

DEVI f32x4 mfma16(u32x4 a, u32x4 b, f32x4 c){
  return __builtin_amdgcn_mfma_f32_16x16x32_bf16(
      __builtin_bit_cast(bf16x8, a), __builtin_bit_cast(bf16x8, b), c, 0, 0, 0);
}

// byte-XOR swizzle (G4) for 512B rows of the LDS x^T image
DEVI int swz8(int m){ return ((m ^ (m >> 3)) & 7) << 4; }

// async global->LDS, 16B per lane; LDS base must be wave-uniform
typedef __attribute__((address_space(3))) unsigned int as3_u32;
typedef __attribute__((address_space(1))) const unsigned int as1_u32;
DEVI void gload16(const void* g, void* l){
  __builtin_amdgcn_global_load_lds((as1_u32*)g, (as3_u32*)l, 16, 0, 0);
}
// stage one 32KB linear image (global -> LDS), async, 8 waves cooperative
DEVI void stage_tile(const char* src, void* buf, int w, int lane){
  #pragma unroll
  for (int i = 0; i < 4; ++i){
    int ub = w * 1024 + i * 8192;               // wave-uniform LDS base
    gload16(src + ub + lane * 16, (char*)buf + ub);
  }
}

// --- fp32 x-tile [256 c][64 m] -> registers -> swizzled bf16 LDS image ------
DEVI void stage_load(const float* __restrict__ xb, int m0, int tid, float4v* r){
  #pragma unroll
  for (int it = 0; it < 2; ++it){
    int cq = (tid >> 4) + it * 32;     // 0..63 -> c0 = 4*cq
    int mq = tid & 15;                 // 0..15 -> ml0 = 4*mq
    const float* p = xb + (size_t)(cq * 4) * 4096 + m0 + mq * 4;
    r[it*4+0] = *(const float4v*)(p);
    r[it*4+1] = *(const float4v*)(p + 4096);
    r[it*4+2] = *(const float4v*)(p + 8192);
    r[it*4+3] = *(const float4v*)(p + 12288);
  }
}
DEVI void stage_write(unsigned short* xT, int tid, const float4v* r){
  #pragma unroll
  for (int it = 0; it < 2; ++it){
    int cq = (tid >> 4) + it * 32;
    int mq = tid & 15;
    int c0 = cq * 4, ml0 = mq * 4;
    #pragma unroll
    for (int j = 0; j < 4; ++j){
      int m = ml0 + j;
      unsigned int lo = pk2(r[it*4+0][j], r[it*4+1][j]);
      unsigned int hi = pk2(r[it*4+2][j], r[it*4+3][j]);
      int off = m * 512 + ((c0 * 2) ^ swz8(m));
      unsigned long long v = (unsigned long long)lo | ((unsigned long long)hi << 32);
      *(unsigned long long*)((char*)xT + off) = v;
    }
  }
}
// de-swizzle dump: LDS x^T tile -> global frag-order image (contiguous store)
DEVI void dump_tile_sw(const unsigned short* xT, unsigned short* dst, int tid){
  #pragma unroll
  for (int i = 0; i < 4; ++i){
    int f = i * 512 + tid;             // frag index 0..2047
    int lane = f & 63, nt = (f >> 6) & 3, kk = f >> 8;
    int m = nt * 16 + (lane & 15);
    int col = (kk * 64 + (lane >> 4) * 16) ^ swz8(m);
    u32x4 v = *(const u32x4*)((const char*)xT + m * 512 + col);
    *(u32x4*)((char*)dst + (size_t)f * 16) = v;
  }
}

// ---------------- kernel 0: weights -> bf16 fragment-order pack -------------
// wkvf: [h][ot 0..3][kk 0..7][lane 0..63] x 16B ; ot 0,1 = Wk rows, 2,3 = Wv.
// wqf : [h][ot 0..1][kk 0..7][lane 0..63] x 16B.
__global__ void wconv(const float* __restrict__ wq, const float* __restrict__ wk,
                      const float* __restrict__ wv,
                      unsigned short* __restrict__ wkvf, unsigned short* __restrict__ wqf){
  int t = blockIdx.x * 256 + threadIdx.x;   // 24576 threads
  if (t < 16384){                           // wkvf frag slots
    int lane = t & 63, kk = (t >> 6) & 7, ot = (t >> 9) & 3, h = t >> 11;
    int l15 = lane & 15, hi = lane >> 4;
    const float* src = (ot < 2) ? (wk + (size_t)(h * 32 + ot * 16 + l15) * 256)
                                : (wv + (size_t)(h * 32 + (ot - 2) * 16 + l15) * 256);
    src += kk * 32 + hi * 8;
    unsigned short* dst = wkvf + (size_t)t * 8;
    #pragma unroll
    for (int j = 0; j < 8; ++j) dst[j] = f2bf(src[j]);
  } else if (t < 24576){                    // wqf frag slots
    int u = t - 16384;
    int lane = u & 63, kk = (u >> 6) & 7, ot = (u >> 9) & 1, h = u >> 10;
    int l15 = lane & 15, hi = lane >> 4;
    const float* src = wq + (size_t)(h * 32 + ot * 16 + l15) * 256 + kk * 32 + hi * 8;
    unsigned short* dst = wqf + (size_t)u * 8;
    #pragma unroll
    for (int j = 0; j < 8; ++j) dst[j] = f2bf(src[j]);
  }
}

// --- one 64-m subtile from the SWIZZLED LDS tile: K/V projection + fold -----
DEVI void compute_sub_sw(const unsigned short* __restrict__ xT,
                         const unsigned short* __restrict__ wkvf,
                         int w, int l15, int hi, int lane,
                         f32x4 (&kvacc)[2][2], f32x4 (&ksacc)[2], u32x4 ones){
  #pragma unroll
  for (int g = 0; g < 2; ++g){              // two 32-m groups: acc stays [2][4]
    f32x4 acc[2][4];                        // [n2][ot: 0,1=K, 2,3=V]
    #pragma unroll
    for (int a1 = 0; a1 < 2; ++a1)
      #pragma unroll
      for (int a2 = 0; a2 < 4; ++a2) acc[a1][a2] = f32x4{0.f,0.f,0.f,0.f};

    #pragma unroll
    for (int kk = 0; kk < 8; ++kk){
      u32x4 xf[2];
      #pragma unroll
      for (int n2 = 0; n2 < 2; ++n2){
        int m = (g * 2 + n2) * 16 + l15;
        xf[n2] = *(const u32x4*)((const char*)xT + m * 512 + ((kk * 64 + hi * 16) ^ swz8(m)));
      }
      #pragma unroll
      for (int ot = 0; ot < 4; ++ot){
        u32x4 wf = *(const u32x4*)(wkvf + ((((size_t)w * 4 + ot) * 8 + kk) * 64 + lane) * 8);
        #pragma unroll
        for (int n2 = 0; n2 < 2; ++n2) acc[n2][ot] = mfma16(xf[n2], wf, acc[n2][ot]);
      }
    }
    // pack bf16 frags in-register; fold into KV / ksum accumulators
    u32x4 kf[2], vf[2];
    #pragma unroll
    for (int t2 = 0; t2 < 2; ++t2){
      kf[t2][0] = pk2(feat(acc[0][t2][0]), feat(acc[0][t2][1]));
      kf[t2][1] = pk2(feat(acc[0][t2][2]), feat(acc[0][t2][3]));
      kf[t2][2] = pk2(feat(acc[1][t2][0]), feat(acc[1][t2][1]));
      kf[t2][3] = pk2(feat(acc[1][t2][2]), feat(acc[1][t2][3]));
      vf[t2][0] = pk2(acc[0][t2+2][0], acc[0][t2+2][1]);
      vf[t2][1] = pk2(acc[0][t2+2][2], acc[0][t2+2][3]);
      vf[t2][2] = pk2(acc[1][t2+2][0], acc[1][t2+2][1]);
      vf[t2][3] = pk2(acc[1][t2+2][2], acc[1][t2+2][3]);
    }
    #pragma unroll
    for (int ct = 0; ct < 2; ++ct){
      #pragma unroll
      for (int dt = 0; dt < 2; ++dt)
        kvacc[ct][dt] = mfma16(kf[ct], vf[dt], kvacc[ct][dt]);
      ksacc[ct] = mfma16(kf[ct], ones, ksacc[ct]);
    }
  }
}

// ---------------- kernel 1: FUSED x-convert + ximg dump + K/V partials ------
// grid (32 chunks, 16 batches), 512 threads = 8 waves = 8 heads; 2 subtiles.
__global__ void __launch_bounds__(512) xkv(const float* __restrict__ x,
        const unsigned short* __restrict__ wkvf,
        unsigned short* __restrict__ ximg,
        float* __restrict__ kvp, float* __restrict__ ksp){
  __shared__ __align__(16) unsigned short xT[2][16384];   // 64KB double-buffer
  const int tid = threadIdx.x, lane = tid & 63, w = tid >> 6;
  const int l15 = lane & 15, hi = lane >> 4;
  const int ch = blockIdx.x, b = blockIdx.y;
  const float* xb = x + (size_t)b * (256 * 4096);
  unsigned short* img = ximg + ((size_t)b * 64 + ch * 2) * 16384;

  f32x4 kvacc[2][2];
  f32x4 ksacc[2];
  #pragma unroll
  for (int i = 0; i < 2; ++i){
    ksacc[i] = f32x4{0.f,0.f,0.f,0.f};
    #pragma unroll
    for (int j = 0; j < 2; ++j) kvacc[i][j] = f32x4{0.f,0.f,0.f,0.f};
  }
  u32x4 ones = {0u,0u,0u,0u};               // B-frag: column d=0 all-ones -> ksum
  if (l15 == 0){ ones[0] = ones[1] = ones[2] = ones[3] = 0x3f803f80u; }

  float4v rs[8];
  stage_load(xb, ch * 128, tid, rs);
  stage_write(xT[0], tid, rs);
  __syncthreads();                                    // tile 0 ready
  stage_load(xb, ch * 128 + 64, tid, rs);             // issue tile-1 loads early
  compute_sub_sw(xT[0], wkvf, w, l15, hi, lane, kvacc, ksacc, ones);
  dump_tile_sw(xT[0], img, tid);                      // dump after MFMA issue
  stage_write(xT[1], tid, rs);                        // write late (latency hidden)
  __syncthreads();                                    // tile 1 ready
  compute_sub_sw(xT[1], wkvf, w, l15, hi, lane, kvacc, ksacc, ones);
  dump_tile_sw(xT[1], img + 16384, tid);

  // partial stores: kvp [b][32 ch][8 h][32 c][32 d], ksp [b][32 ch][8 h][32 c]
  size_t base = (((size_t)b * 32 + ch) * 8 + w) * 1024;
  #pragma unroll
  for (int ct = 0; ct < 2; ++ct){
    #pragma unroll
    for (int dt = 0; dt < 2; ++dt){
      #pragma unroll
      for (int r = 0; r < 4; ++r){
        int c = ct * 16 + hi * 4 + r, d = dt * 16 + l15;
        kvp[base + c * 32 + d] = kvacc[ct][dt][r];
      }
    }
  }
  if (l15 == 0){
    size_t kb = (((size_t)b * 32 + ch) * 8 + w) * 32;
    #pragma unroll
    for (int ct = 0; ct < 2; ++ct)
      #pragma unroll
      for (int r = 0; r < 4; ++r) ksp[kb + ct * 16 + hi * 4 + r] = ksacc[ct][r];
  }
}

// ---------------- kernel 2: reduce partials -> KV^T bf16 [b][h][d][pos(c)], ksum bf16
// slot permutation matching q's in-register frag: pos(c) = ((c>>2)&3)*8 + (c>>4)*4 + (c&3)
__global__ void k_red(const float* __restrict__ kvp, const float* __restrict__ ksp,
                      unsigned short* __restrict__ kvt, unsigned short* __restrict__ ksb){
  int t = blockIdx.x * 256 + threadIdx.x;   // 32768 threads: (b,h,c,dq)
  int dq = t & 7;            // d-quad
  int c  = (t >> 3) & 31;
  int h  = (t >> 8) & 7;
  int b  = t >> 11;
  float4v s = {0.f,0.f,0.f,0.f};
  for (int c2 = 0; c2 < 32; ++c2){
    const float* p = kvp + ((((size_t)b * 32 + c2) * 8 + h) * 1024) + c * 32 + dq * 4;
    float4v r = *(const float4v*)p;
    s.x += r.x; s.y += r.y; s.z += r.z; s.w += r.w;
  }
  int pos = ((c >> 2) & 3) * 8 + ((c >> 4) << 2) + (c & 3);
  unsigned short* q = kvt + ((size_t)b * 8 + h) * 1024;
  q[(dq * 4 + 0) * 32 + pos] = f2bf(s.x);
  q[(dq * 4 + 1) * 32 + pos] = f2bf(s.y);
  q[(dq * 4 + 2) * 32 + pos] = f2bf(s.z);
  q[(dq * 4 + 3) * 32 + pos] = f2bf(s.w);
  if (dq == 0){
    float ks = 0.f;
    for (int c2 = 0; c2 < 32; ++c2)
      ks += ksp[(((size_t)b * 32 + c2) * 8 + h) * 32 + c];
    ksb[((size_t)b * 8 + h) * 32 + pos] = f2bf(ks);
  }
}

// --- one 64-m subtile of k_q: Q projection + out = KV^T q / denom -----------
// xT = frag-order tile in LDS (linear); fragment reads are contiguous 1KB
// wave reads -> conflict-free, no swizzle.
DEVI void q_sub(const unsigned short* __restrict__ xT,
                const unsigned short* __restrict__ wqf,
                u32x4 afkv0, u32x4 afkv1, u32x4 afd,
                int w, int l15, int hi, int lane, float* __restrict__ ob){
  f32x4 qa[2][4];                           // [ot = c-tile][nt = m-tile]
  #pragma unroll
  for (int a1 = 0; a1 < 2; ++a1)
    #pragma unroll
    for (int a2 = 0; a2 < 4; ++a2) qa[a1][a2] = f32x4{0.f,0.f,0.f,0.f};

  #pragma unroll
  for (int kk = 0; kk < 8; ++kk){
    u32x4 xf[4];
    #pragma unroll
    for (int nt = 0; nt < 4; ++nt)
      xf[nt] = *(const u32x4*)(xT + (((size_t)kk * 4 + nt) * 64 + lane) * 8);
    #pragma unroll
    for (int ot = 0; ot < 2; ++ot){
      u32x4 wf = *(const u32x4*)(wqf + ((((size_t)w * 2 + ot) * 8 + kk) * 64 + lane) * 8);
      #pragma unroll
      for (int nt = 0; nt < 4; ++nt) qa[ot][nt] = mfma16(wf, xf[nt], qa[ot][nt]);
    }
  }

  #pragma unroll
  for (int nt = 0; nt < 4; ++nt){
    // q B-frag in-register: lane l15 = m, slots = c (ot0 r0..3, ot1 r0..3)
    u32x4 bq;
    bq[0] = pk2(feat(qa[0][nt][0]), feat(qa[0][nt][1]));
    bq[1] = pk2(feat(qa[0][nt][2]), feat(qa[0][nt][3]));
    bq[2] = pk2(feat(qa[1][nt][0]), feat(qa[1][nt][1]));
    bq[3] = pk2(feat(qa[1][nt][2]), feat(qa[1][nt][3]));

    f32x4 o0 = {0.f,0.f,0.f,0.f}, o1 = {0.f,0.f,0.f,0.f}, dn = {0.f,0.f,0.f,0.f};
    o0 = mfma16(afkv0, bq, o0);
    o1 = mfma16(afkv1, bq, o1);
    dn = mfma16(afd, bq, dn);
    float dv = __shfl(dn[0], l15, 64);       // lanes hi==0 hold denom[m] in reg0
    float inv = 1.0f / fmaxf(dv, 1e-6f);
    #pragma unroll
    for (int r = 0; r < 4; ++r){
      ob[(size_t)(hi * 4 + r) * 4096 + nt * 16 + l15]      = o0[r] * inv;
      ob[(size_t)(16 + hi * 4 + r) * 4096 + nt * 16 + l15] = o1[r] * inv;
    }
  }
}

// ---------------- kernel 3: Q projection + apply KV -------------------------
// grid (32 chunks, 16 batches), 512 threads = 8 waves = 8 heads; 2 subtiles.
// gload_lds staged, linear frag-order copy (at BW roofline since R10).
__global__ void __launch_bounds__(512) k_q(const unsigned short* __restrict__ ximg,
        const unsigned short* __restrict__ wqf,
        const unsigned short* __restrict__ kvt,
        const unsigned short* __restrict__ ksb,
        float* __restrict__ out){
  __shared__ __align__(16) unsigned short xT[2][16384];   // 64KB double-buffer
  const int tid = threadIdx.x, lane = tid & 63, w = tid >> 6;
  const int l15 = lane & 15, hi = lane >> 4;
  const int ch = blockIdx.x, b = blockIdx.y;
  const char* src = (const char*)(ximg + ((size_t)b * 64 + ch * 2) * 16384);

  // KV^T / ksum frags (slot-permuted storage from k_red matches q packing)
  size_t kvbase = ((size_t)b * 8 + w) * 1024;
  u32x4 afkv0 = *(const u32x4*)(kvt + kvbase + (size_t)l15 * 32 + hi * 8);        // d = l15
  u32x4 afkv1 = *(const u32x4*)(kvt + kvbase + (size_t)(16 + l15) * 32 + hi * 8); // d = 16+l15
  u32x4 afd = {0u,0u,0u,0u};                 // row0 = ksum -> D[0][m] = denom
  if (l15 == 0) afd = *(const u32x4*)(ksb + ((size_t)b * 8 + w) * 32 + hi * 8);

  stage_tile(src, xT[0], w, lane);
  __syncthreads();                                   // t0 ready
  stage_tile(src + 32768, xT[1], w, lane);           // issue t1 async

  float* ob = out + ((size_t)b * 256 + w * 32) * 4096 + ch * 128;
  q_sub(xT[0], wqf, afkv0, afkv1, afd, w, l15, hi, lane, ob);
  __syncthreads();                                   // t1 drained
  q_sub(xT[1], wqf, afkv0, afkv1, afd, w, l15, hi, lane, ob + 64);
}

extern "C" void kernel_launch(void* const* d_in, const int* in_sizes, int n_in,
                              void* d_out, int out_size, void* d_ws, size_t ws_size,
                              hipStream_t stream) {
  const float* x  = (const float*)d_in[0];
  const float* wq = (const float*)d_in[1];
  const float* wk = (const float*)d_in[2];
  const float* wv = (const float*)d_in[3];
  float* out = (float*)d_out;
  char* ws = (char*)d_ws;

  // ws layout (bytes): total ~49.5 MB
  unsigned short* wkvf = (unsigned short*)(ws);                  // 262144
  unsigned short* wqf  = (unsigned short*)(ws + 262144);         // 131072
  unsigned short* kvt  = (unsigned short*)(ws + 393216);         // 262144
  unsigned short* ksb  = (unsigned short*)(ws + 655360);         // 8192
  float* kvp = (float*)(ws + 1048576);                           // 16777216
  float* ksp = (float*)(ws + 17825792);                          // 524288
  unsigned short* ximg = (unsigned short*)(ws + 18350080);       // 33554432

  hipLaunchKernelGGL(wconv, dim3(96), dim3(256), 0, stream, wq, wk, wv, wkvf, wqf);
  hipLaunchKernelGGL(xkv,   dim3(32, 16), dim3(512), 0, stream, x, wkvf, ximg, kvp, ksp);
  hipLaunchKernelGGL(k_red, dim3(128), dim3(256), 0, stream, kvp, ksp, kvt, ksb);
  hipLaunchKernelGGL(k_q,   dim3(32, 16), dim3(512), 0, stream, ximg, wqf, kvt, ksb, out);
}